// Round 12
// baseline (219.119 us; speedup 1.0000x reference)
//
#include <hip/hip_runtime.h>
#include <hip/hip_bf16.h>
#include <math.h>
#include <stdint.h>

typedef __attribute__((ext_vector_type(8))) short short8;
typedef __attribute__((ext_vector_type(4))) float float4v;

#define DEV static __device__ __forceinline__

DEV float bflo(unsigned int u) { union { unsigned int i; float f; } v; v.i = u << 16; return v.f; }
DEV float bfhi(unsigned int u) { union { unsigned int i; float f; } v; v.i = u & 0xffff0000u; return v.f; }
DEV unsigned short f2bf(float f) {
    union { float f; unsigned int i; } v; v.f = f;
    unsigned int x = v.i;
    return (unsigned short)((x + 0x7fffu + ((x >> 16) & 1u)) >> 16);
}
DEV unsigned int pack2(float a, float b) { return (unsigned int)f2bf(a) | ((unsigned int)f2bf(b) << 16); }
#if __has_builtin(__builtin_amdgcn_cvt_pk_bf16_f32)
DEV unsigned int pack2_fast(float a, float b) {
    typedef __attribute__((ext_vector_type(2))) short short2v;
    short2v r = __builtin_amdgcn_cvt_pk_bf16_f32(a, b);
    union { short2v s; unsigned int u; } v; v.s = r; return v.u;
}
#else
DEV unsigned int pack2_fast(float a, float b) { return pack2(a, b); }
#endif
DEV void unpack8(uint4 u, float* f) {
    f[0]=bflo(u.x); f[1]=bfhi(u.x); f[2]=bflo(u.y); f[3]=bfhi(u.y);
    f[4]=bflo(u.z); f[5]=bfhi(u.z); f[6]=bflo(u.w); f[7]=bfhi(u.w);
}

DEV void async16(const unsigned short* g, unsigned short* l) {
    __builtin_amdgcn_global_load_lds(
        (const __attribute__((address_space(1))) unsigned int*)g,
        (__attribute__((address_space(3))) unsigned int*)l, 16, 0, 0);
}

// ---------------------------------------------------------------------------
// K0: prep = cast f32->bf16 (lt, rt, 4 match kernels) + w1 transpose
// ---------------------------------------------------------------------------
__global__ __launch_bounds__(256) void prep_kernel(const float* __restrict__ lt,
                                                   const float* __restrict__ rt,
                                                   const float* __restrict__ kf,
                                                   const float* __restrict__ kmp,
                                                   const float* __restrict__ ka,
                                                   const float* __restrict__ km,
                                                   const float* __restrict__ w1,
                                                   unsigned short* __restrict__ ltb,
                                                   unsigned short* __restrict__ rtb,
                                                   unsigned short* __restrict__ kb,
                                                   unsigned short* __restrict__ w1t) {
    __shared__ float tile[32][33];
    int bid = blockIdx.x, t = threadIdx.x;
    if (bid < 1024) {
        bool isRt = bid >= 512;
        int base = (isRt ? (bid - 512) : bid) * 8;
        int rl = t >> 7;
        int c  = t & 127;
        const float* srcb = isRt ? rt : lt;
        unsigned short* dstb = isRt ? rtb : ltb;
        #pragma unroll
        for (int p = 0; p < 4; ++p) {
            int row = base + p * 2 + rl;
            const float* src = srcb + (size_t)row * 512;
            float4 v = *(const float4*)(src + c * 4);
            ushort4 o;
            o.x = f2bf(v.x); o.y = f2bf(v.y); o.z = f2bf(v.z); o.w = f2bf(v.w);
            *(ushort4*)(dstb + (size_t)row * 512 + c * 4) = o;
        }
    } else if (bid < 1152) {
        int kbk = bid - 1024;
        int ksel = kbk >> 5;
        const float* src = (ksel == 0) ? kf : (ksel == 1) ? kmp : (ksel == 2) ? ka : km;
        int off = (kbk & 31) * 1024 + t * 4;
        float4 v = *(const float4*)(src + off);
        ushort4 o;
        o.x = f2bf(v.x); o.y = f2bf(v.y); o.z = f2bf(v.z); o.w = f2bf(v.w);
        *(ushort4*)(kb + ksel * 32768 + off) = o;
    } else {
        int b2 = bid - 1152;
        int d0 = (b2 & 15) * 32, a0 = (b2 >> 4) * 32;
        int r = t >> 5, c = t & 31;
        #pragma unroll
        for (int i = 0; i < 32; i += 8)
            tile[r + i][c] = w1[(size_t)(d0 + r + i) * 128 + a0 + c];
        __syncthreads();
        #pragma unroll
        for (int i = 0; i < 32; i += 8)
            w1t[(size_t)(a0 + r + i) * 512 + d0 + c] = f2bf(tile[c][r + i]);
    }
}

// ---------------------------------------------------------------------------
// K1: uber = mpool [0,2048) + argmax [2048,2560) + proj [2560,2816)
// mpool: R7 structure — single ltS, double async rtL, reg-prefetch lt/K,
// XCD swizzle, 2 barriers/k0, 3 blocks/CU. argmax computes rsq in-block (f64).
// ---------------------------------------------------------------------------
__global__ __launch_bounds__(256, 3) void uber_kernel(
        const unsigned short* __restrict__ ltb,
        const unsigned short* __restrict__ rtb,
        const unsigned short* __restrict__ kmb,
        const unsigned short* __restrict__ w1t,
        const float* __restrict__ diag,
        unsigned short* __restrict__ a_all,
        const float* __restrict__ ltf,
        const float* __restrict__ rtf,
        int* __restrict__ idxout,
        float* __restrict__ out) {
    __shared__ __align__(16) unsigned char smem[52224];
    int bx = blockIdx.x;
    int t = threadIdx.x;
    int wave = t >> 6, lane = t & 63;
    int q = lane >> 4, col = lane & 15, kq = q * 8;

    if (bx < 2048) {
        // ================= mpool role =================
        int xcd = bx & 7, jj = bx >> 3;
        int b = xcd * 4 + (jj >> 6);
        int m = jj & 63;
        unsigned short (*ltS)[72] = (unsigned short(*)[72])smem;        // 18432 B
        unsigned short* rtL = (unsigned short*)(smem + 18432);          // 2 x 16384 B, swizzled
        float (*mx)[2] = (float(*)[2])(smem + 18432 + 32768);          // 1024 B
        int wl = wave & 1, wr = wave >> 1;
        const unsigned short* ltp = ltb + (size_t)b * 65536;
        const unsigned short* rtp = rtb + (size_t)b * 65536;
        const unsigned short* kr = kmb + (size_t)m * 512;
        int srow = t >> 3, cg8 = t & 7, cg = cg8 * 8;
        int gsw = (cg8 ^ (srow & 7)) * 8;   // source-swizzled column group
        int wbase = (t & ~63) * 8;          // wave-uniform LDS base (shorts)

        // prologue: async rt(k0=0) -> buf0, lt/K(k0=0) -> regs
        #pragma unroll
        for (int it = 0; it < 4; ++it)
            async16(rtp + (size_t)(it * 32 + srow) * 512 + gsw,
                    rtL + it * 2048 + wbase);
        uint4 pk = *(const uint4*)(kr + cg);
        uint4 plt[4];
        #pragma unroll
        for (int it = 0; it < 4; ++it)
            plt[it] = *(const uint4*)(ltp + (size_t)(it * 32 + srow) * 512 + cg);

        float4v acc[4][4] = {};
        for (int k0i = 0; k0i < 8; ++k0i) {
            // scale+write ltS from prefetched regs
            float kf8[8]; unpack8(pk, kf8);
            #pragma unroll
            for (int it = 0; it < 4; ++it) {
                int row = it * 32 + srow;
                float lf[8]; unpack8(plt[it], lf);
                uint4 s;
                s.x = pack2_fast(lf[0] * kf8[0], lf[1] * kf8[1]);
                s.y = pack2_fast(lf[2] * kf8[2], lf[3] * kf8[3]);
                s.z = pack2_fast(lf[4] * kf8[4], lf[5] * kf8[5]);
                s.w = pack2_fast(lf[6] * kf8[6], lf[7] * kf8[7]);
                *(uint4*)&ltS[row][cg] = s;
            }
            __syncthreads();   // rt(k0) landed + lt staged
            if (k0i < 7) {     // prefetch k0+1: async rt + lt/K regs (fly during MFMA)
                int k0n = (k0i + 1) * 64;
                int bofs = ((k0i + 1) & 1) * 8192;
                #pragma unroll
                for (int it = 0; it < 4; ++it)
                    async16(rtp + (size_t)(it * 32 + srow) * 512 + k0n + gsw,
                            rtL + bofs + it * 2048 + wbase);
                pk = *(const uint4*)(kr + k0n + cg);
                #pragma unroll
                for (int it = 0; it < 4; ++it)
                    plt[it] = *(const uint4*)(ltp + (size_t)(it * 32 + srow) * 512 + k0n + cg);
            }
            const unsigned short* rb = rtL + (k0i & 1) * 8192;
            #pragma unroll
            for (int kk = 0; kk < 64; kk += 32) {
                short8 af[4], bfr[4];
                #pragma unroll
                for (int i = 0; i < 4; ++i)
                    af[i] = *(const short8*)&ltS[wl * 64 + i * 16 + col][kk + kq];
                #pragma unroll
                for (int j = 0; j < 4; ++j) {
                    int row = wr * 64 + j * 16 + col;
                    int slot = ((kk >> 3) + q) ^ (row & 7);
                    bfr[j] = *(const short8*)&rb[row * 64 + slot * 8];
                }
                #pragma unroll
                for (int i = 0; i < 4; ++i)
                    #pragma unroll
                    for (int j = 0; j < 4; ++j)
                        acc[i][j] = __builtin_amdgcn_mfma_f32_16x16x32_bf16(af[i], bfr[j], acc[i][j], 0, 0, 0);
            }
            __syncthreads();   // before ltS overwrite
        }
        #pragma unroll
        for (int i = 0; i < 4; ++i)
            #pragma unroll
            for (int ii = 0; ii < 4; ++ii) {
                float v = fmaxf(fmaxf(acc[i][0][ii], acc[i][1][ii]), fmaxf(acc[i][2][ii], acc[i][3][ii]));
                #pragma unroll
                for (int off = 1; off < 16; off <<= 1) v = fmaxf(v, __shfl_xor(v, off, 64));
                if (col == 0) mx[wl * 64 + i * 16 + q * 4 + ii][wr] = v;
            }
        __syncthreads();
        if (t < 128)
            out[((size_t)(b * 128 + t)) * 259 + 65 + m] = tanhf(fmaxf(mx[t][0], mx[t][1]));

    } else if (bx < 2560) {
        // ================= argmax role =================
        int idA = bx - 2048;
        int xcd = idA & 7, jj = idA >> 3;
        int b = xcd * 4 + (jj >> 4);
        int L0 = (jj & 15) * 8;
        float* ltS = (float*)smem;
        float* buf = (float*)(smem + 16384);
        double* dvs = (double*)(smem + 49152);
        float* wv1 = (float*)(smem + 49152 + 128);
        float* wv2 = wv1 + 16;
        int* wi1 = (int*)(wv2 + 16);
        int* wi2 = wi1 + 16;
        int* candi = wi2 + 16;
        double* rsqS = (double*)(smem + 50176);   // 128 f64
        {
            int row = t >> 5, c0 = (t & 31) * 16;
            const float* src = ltf + ((size_t)(b * 128 + L0 + row)) * 512 + c0;
            #pragma unroll
            for (int i = 0; i < 4; ++i)
                *(float4*)&ltS[row * 512 + c0 + i * 4] = *(const float4*)(src + i * 4);
        }
        {   // per-block rsq (f64): r = t>>1 covers all 128 rows, 2 half-row chunks
            int r = t >> 1, half = t & 1;
            const float* rrow = rtf + ((size_t)(b * 128 + r)) * 512 + half * 256;
            double s = 0.0;
            #pragma unroll 4
            for (int k = 0; k < 256; ++k) s = fma((double)rrow[k], (double)rrow[k], s);
            s += __shfl_xor(s, 1, 64);
            if (half == 0) rsqS[r] = 1.0 / sqrt(s);
        }
        int lg = t >> 7;
        int rg = (t >> 2) & 31;
        int ds = t & 3;
        float acc[4][4] = {{0.f}};
        for (int p = 0; p < 8; ++p) {
            __syncthreads();
            {
                int row = t >> 1, c0 = (t & 1) * 32;
                const float* src = rtf + ((size_t)(b * 128 + row)) * 512 + p * 64 + c0;
                float f[32];
                #pragma unroll
                for (int i = 0; i < 8; ++i)
                    *(float4*)&f[i * 4] = *(const float4*)(src + i * 4);
                int base = row * 64;
                #pragma unroll
                for (int gg = 0; gg < 4; ++gg) {
                    int g = (t & 1) * 4 + gg;
                    int o = ((g ^ (row & 7)) * 8);
                    #pragma unroll
                    for (int k = 0; k < 8; ++k) buf[base + o + k] = f[gg * 8 + k];
                }
            }
            __syncthreads();
            #pragma unroll
            for (int sub = 0; sub < 2; ++sub) {
                int dloc = ds * 16 + sub * 8;
                int dglob = p * 64 + dloc;
                float a[4][8];
                #pragma unroll
                for (int i = 0; i < 4; ++i)
                    #pragma unroll
                    for (int k = 0; k < 8; ++k) a[i][k] = ltS[(lg * 4 + i) * 512 + dglob + k];
                int g = dloc >> 3;
                #pragma unroll
                for (int j = 0; j < 4; ++j) {
                    int r = rg + j * 32;
                    const float* rp = &buf[r * 64 + ((g ^ (r & 7)) * 8)];
                    float rv[8];
                    #pragma unroll
                    for (int k = 0; k < 8; ++k) rv[k] = rp[k];
                    #pragma unroll
                    for (int i = 0; i < 4; ++i)
                        #pragma unroll
                        for (int k = 0; k < 8; ++k)
                            acc[i][j] = fmaf(a[i][k], rv[k], acc[i][j]);
                }
            }
        }
        #pragma unroll
        for (int i = 0; i < 4; ++i)
            #pragma unroll
            for (int j = 0; j < 4; ++j) {
                acc[i][j] += __shfl_xor(acc[i][j], 1, 64);
                acc[i][j] += __shfl_xor(acc[i][j], 2, 64);
            }
        float v1[4], v2[4]; int i1[4], i2[4];
        #pragma unroll
        for (int i = 0; i < 4; ++i) {
            v1[i] = -3.0e38f; v2[i] = -3.0e38f; i1[i] = 0; i2[i] = 1;
            #pragma unroll
            for (int j = 0; j < 4; ++j) {
                int r = rg + j * 32;
                float s = acc[i][j] * (float)rsqS[r];
                if (s > v1[i]) { v2[i] = v1[i]; i2[i] = i1[i]; v1[i] = s; i1[i] = r; }
                else if (s > v2[i]) { v2[i] = s; i2[i] = r; }
            }
        }
        #pragma unroll
        for (int off = 4; off < 64; off <<= 1) {
            #pragma unroll
            for (int i = 0; i < 4; ++i) {
                float u1 = __shfl_xor(v1[i], off, 64); int j1 = __shfl_xor(i1[i], off, 64);
                float u2 = __shfl_xor(v2[i], off, 64); int j2 = __shfl_xor(i2[i], off, 64);
                if (u1 > v1[i]) {
                    float ov = v1[i]; int oi = i1[i];
                    v1[i] = u1; i1[i] = j1;
                    if (u2 > ov) { v2[i] = u2; i2[i] = j2; } else { v2[i] = ov; i2[i] = oi; }
                } else if (u1 > v2[i]) { v2[i] = u1; i2[i] = j1; }
            }
        }
        if (lane == 0) {
            #pragma unroll
            for (int i = 0; i < 4; ++i) {
                int l = lg * 4 + i, h = wave & 1;
                wv1[l * 2 + h] = v1[i]; wi1[l * 2 + h] = i1[i];
                wv2[l * 2 + h] = v2[i]; wi2[l * 2 + h] = i2[i];
            }
        }
        __syncthreads();
        if (t < 8) {
            float a1 = wv1[t * 2], a2 = wv2[t * 2]; int ai1 = wi1[t * 2], ai2 = wi2[t * 2];
            float b1 = wv1[t * 2 + 1], b2 = wv2[t * 2 + 1]; int bi1 = wi1[t * 2 + 1], bi2 = wi2[t * 2 + 1];
            int ri1, ri2;
            if (b1 > a1) {
                ri1 = bi1;
                if (b2 > a1) { ri2 = bi2; } else { ri2 = ai1; }
            } else {
                ri1 = ai1;
                if (b1 > a2) { ri2 = bi1; } else { ri2 = ai2; }
            }
            candi[t * 2] = ri1; candi[t * 2 + 1] = ri2;
            (void)a2; (void)b2; (void)ai2; (void)bi2;
        }
        __syncthreads();
        {
            int dotid = t >> 4;
            int sub = t & 15;
            int l = dotid >> 1, c = dotid & 1;
            int r = candi[l * 2 + c];
            const float* lrow = ltf + ((size_t)(b * 128 + L0 + l)) * 512;
            const float* rrow = rtf + ((size_t)(b * 128 + r)) * 512;
            double s = 0.0;
            #pragma unroll 8
            for (int k = 0; k < 32; ++k) {
                int d = sub * 32 + k;
                s = fma((double)lrow[d], (double)rrow[d], s);
            }
            #pragma unroll
            for (int off = 1; off < 16; off <<= 1) s += __shfl_xor(s, off, 64);
            if (sub == 0) dvs[l * 2 + c] = s * rsqS[r];
        }
        __syncthreads();
        if (t < 8) {
            int ia = candi[t * 2], ib = candi[t * 2 + 1];
            double va = dvs[t * 2], vb = dvs[t * 2 + 1];
            int res = (vb > va || (vb == va && ib < ia)) ? ib : ia;
            idxout[b * 128 + L0 + t] = res;
        }

    } else {
        // ================= proj role =================
        int R0 = (bx - 2560) * 32;
        unsigned short (*aS)[72] = (unsigned short(*)[72])smem;
        unsigned short (*bS)[72] = (unsigned short(*)[72])(smem + 4608);
        float* diagS = (float*)(smem + 4608 + 18432);
        int wl = wave & 1, wr = wave >> 1;
        if (t < 128) diagS[t] = diag[t];
        const unsigned short* src = (R0 < 4096) ? (ltb + (size_t)R0 * 512) : (rtb + (size_t)(R0 - 4096) * 512);
        float4v acc[4] = {};
        for (int k0 = 0; k0 < 512; k0 += 64) {
            {
                int row = t >> 3, cg = (t & 7) * 8;
                *(uint4*)&aS[row][cg] = *(const uint4*)(src + (size_t)row * 512 + k0 + cg);
            }
            #pragma unroll
            for (int it = 0; it < 4; ++it) {
                int id = it * 256 + t;
                int row = id >> 3, cg = (id & 7) * 8;
                *(uint4*)&bS[row][cg] = *(const uint4*)(w1t + (size_t)row * 512 + k0 + cg);
            }
            __syncthreads();
            #pragma unroll
            for (int kk = 0; kk < 64; kk += 32) {
                short8 af = *(const short8*)&aS[wl * 16 + col][kk + kq];
                #pragma unroll
                for (int j = 0; j < 4; ++j) {
                    short8 bf = *(const short8*)&bS[wr * 64 + j * 16 + col][kk + kq];
                    acc[j] = __builtin_amdgcn_mfma_f32_16x16x32_bf16(af, bf, acc[j], 0, 0, 0);
                }
            }
            __syncthreads();
        }
        bool isLt = (R0 < 4096);
        #pragma unroll
        for (int j = 0; j < 4; ++j)
            #pragma unroll
            for (int ii = 0; ii < 4; ++ii) {
                int rowl = wl * 16 + q * 4 + ii;
                int n = wr * 64 + j * 16 + col;
                float v = tanhf(acc[j][ii]);
                if (isLt) v *= diagS[n];
                a_all[((size_t)(R0 + rowl)) * 128 + n] = f2bf(v);
            }
    }
}

// ---------------------------------------------------------------------------
// K2: tail = attn+fused-mode1 [0,256) + mpmatch both-halves [256,768)
// 512 threads; role by blockIdx.x.
// ---------------------------------------------------------------------------
__global__ __launch_bounds__(512, 1) void tail_kernel(
        const unsigned short* __restrict__ a_all,
        const unsigned short* __restrict__ rtb,
        const float* __restrict__ ltf,
        const unsigned short* __restrict__ kb,
        const float* __restrict__ hfw,
        const float* __restrict__ hbw,
        const int* __restrict__ idxp,
        float* __restrict__ out) {
    __shared__ __align__(16) unsigned char smem[99584];
    int bx = blockIdx.x;
    int t = threadIdx.x;
    int wave = t >> 6, lane = t & 63;
    int q = lane >> 4, col = lane & 15, kq = q * 8;

    if (bx < 256) {
        // ================= attn role =================
        int b = bx & 31, lg = bx >> 5;
        int L0 = lg * 16;
        unsigned short (*altS)[136]  = (unsigned short(*)[136])(smem);          // 4352
        unsigned short (*artS)[136]  = (unsigned short(*)[136])(smem + 4352);   // 34816
        unsigned short (*rtS)[512]   = (unsigned short(*)[512])(smem + 39168);  // 16384
        unsigned short (*prodsF)[520]= (unsigned short(*)[520])(smem + 55552);  // 16640
        float (*P)[132]  = (float(*)[132])(smem + 72192);                       // 8448
        float (*pmax)[8] = (float(*)[8])(smem + 80640);                         // 512
        float (*psum)[8] = (float(*)[8])(smem + 81152);                         // 512
        const unsigned short* kb_att = kb + 2 * 32768;

        if (t < 256) {
            int row = t >> 4, c0 = (t & 15) * 8;
            *(uint4*)&altS[row][c0] = *(const uint4*)(a_all + ((size_t)(b * 128 + L0 + row)) * 128 + c0);
        }
        {
            int row = t >> 2, c0 = (t & 3) * 32;
            const unsigned short* src = a_all + ((size_t)(4096 + b * 128 + row)) * 128 + c0;
            #pragma unroll
            for (int i = 0; i < 4; ++i)
                *(uint4*)&artS[row][c0 + i * 8] = *(const uint4*)(src + i * 8);
        }
        __syncthreads();

        float4v acc = {};
        #pragma unroll
        for (int kk = 0; kk < 128; kk += 32) {
            short8 af = *(const short8*)&altS[col][kk + kq];
            short8 bf = *(const short8*)&artS[wave * 16 + col][kk + kq];
            acc = __builtin_amdgcn_mfma_f32_16x16x32_bf16(af, bf, acc, 0, 0, 0);
        }
        float m4[4], p4[4];
        #pragma unroll
        for (int ii = 0; ii < 4; ++ii) {
            float v = acc[ii];
            #pragma unroll
            for (int off = 1; off < 16; off <<= 1) v = fmaxf(v, __shfl_xor(v, off, 64));
            m4[ii] = v;
        }
        if (col == 0) {
            #pragma unroll
            for (int ii = 0; ii < 4; ++ii) pmax[q * 4 + ii][wave] = m4[ii];
        }
        __syncthreads();
        #pragma unroll
        for (int ii = 0; ii < 4; ++ii) {
            float M = pmax[q * 4 + ii][0];
            #pragma unroll
            for (int w = 1; w < 8; ++w) M = fmaxf(M, pmax[q * 4 + ii][w]);
            p4[ii] = expf(acc[ii] - M);
            float s = p4[ii];
            #pragma unroll
            for (int off = 1; off < 16; off <<= 1) s += __shfl_xor(s, off, 64);
            m4[ii] = s;
        }
        if (col == 0) {
            #pragma unroll
            for (int ii = 0; ii < 4; ++ii) psum[q * 4 + ii][wave] = m4[ii];
        }
        __syncthreads();
        #pragma unroll
        for (int ii = 0; ii < 4; ++ii) {
            float S = psum[q * 4 + ii][0] + psum[q * 4 + ii][1] + psum[q * 4 + ii][2] + psum[q * 4 + ii][3]
                    + psum[q * 4 + ii][4] + psum[q * 4 + ii][5] + psum[q * 4 + ii][6] + psum[q * 4 + ii][7];
            P[q * 4 + ii][wave * 16 + col] = p4[ii] / S;
        }

        int l = t >> 5, cd = t & 31;
        float a8[2][8] = {{0.f}};
        for (int rcb = 0; rcb < 128; rcb += 16) {
            __syncthreads();
            {
                int row = t >> 5, c0 = (t & 31) * 16;
                const unsigned short* src = rtb + ((size_t)(b * 128 + rcb + row)) * 512 + c0;
                *(uint4*)&rtS[row][c0] = *(const uint4*)src;
                *(uint4*)&rtS[row][c0 + 8] = *(const uint4*)(src + 8);
            }
            __syncthreads();
            for (int rr = 0; rr < 16; ++rr) {
                float pr = P[l][rcb + rr];
                #pragma unroll
                for (int pass = 0; pass < 2; ++pass) {
                    uint4 u = *(const uint4*)&rtS[rr][pass * 256 + cd * 8];
                    float f[8]; unpack8(u, f);
                    #pragma unroll
                    for (int k = 0; k < 8; ++k) a8[pass][k] += pr * f[k];
                }
            }
        }

        int grow = b * 128 + L0 + l;
        const float* ltrow = ltf + (size_t)grow * 512;
        float csum = 0.f;
        #pragma unroll
        for (int pass = 0; pass < 2; ++pass) {
            int d0 = pass * 256 + cd * 8;
            float lf[8];
            *(float4*)&lf[0] = *(const float4*)(ltrow + d0);
            *(float4*)&lf[4] = *(const float4*)(ltrow + d0 + 4);
            float pf[8];
            #pragma unroll
            for (int k = 0; k < 8; ++k) { pf[k] = lf[k] * a8[pass][k]; csum += pf[k]; }
            uint4 o;
            o.x = pack2(pf[0], pf[1]); o.y = pack2(pf[2], pf[3]);
            o.z = pack2(pf[4], pf[5]); o.w = pack2(pf[6], pf[7]);
            *(uint4*)&prodsF[l][d0] = o;
        }
        #pragma unroll
        for (int off = 1; off < 32; off <<= 1) csum += __shfl_xor(csum, off, 64);
        if (cd == 0) out[(size_t)grow * 259 + 129] = tanhf(csum);

        unsigned short* Ks = &artS[0][0];
        float* red = (float*)&rtS[0][0];
        for (int half = 0; half < 2; ++half) {
            __syncthreads();
            {
                int row = t >> 4, c0 = (t & 15) * 32;
                const unsigned short* src = kb_att + ((size_t)(half * 32 + row)) * 512 + c0;
                #pragma unroll
                for (int i = 0; i < 4; ++i)
                    *(uint4*)&Ks[row * 520 + c0 + i * 8] = *(const uint4*)(src + i * 8);
            }
            __syncthreads();
            float4v pacc[2] = {};
            #pragma unroll
            for (int kk = 0; kk < 64; kk += 32) {
                short8 af = *(const short8*)&prodsF[col][wave * 64 + kk + kq];
                #pragma unroll
                for (int j = 0; j < 2; ++j) {
                    short8 bf = *(const short8*)&Ks[(j * 16 + col) * 520 + wave * 64 + kk + kq];
                    pacc[j] = __builtin_amdgcn_mfma_f32_16x16x32_bf16(af, bf, pacc[j], 0, 0, 0);
                }
            }
            #pragma unroll
            for (int j = 0; j < 2; ++j)
                #pragma unroll
                for (int ii = 0; ii < 4; ++ii)
                    red[((wave * 2 + j) * 16 + q * 4 + ii) * 16 + col] = pacc[j][ii];
            __syncthreads();
            {
                int ll = t >> 5, jm = t & 31;
                int j = jm >> 4, mc = jm & 15;
                float s = 0.f;
                #pragma unroll
                for (int w = 0; w < 8; ++w) s += red[((w * 2 + j) * 16 + ll) * 16 + mc];
                out[((size_t)(b * 128 + L0 + ll)) * 259 + 130 + half * 32 + jm] = tanhf(s);
            }
        }

    } else {
        // ================= mpmatch role (both 32-m halves concurrently) =====
        int idB = bx - 256;
        int lg = idB & 7, b = (idB >> 3) & 31;
        int mode = (idB >> 8) ? 2 : 0;
        int L0 = lg * 16;
        unsigned short (*prods)[520] = (unsigned short(*)[520])smem;            // 16640
        unsigned short* Ks = (unsigned short*)(smem + 16640);                   // 64*520*2 = 66560
        float* red = (float*)(smem + 83200);                                    // [2][4][2][16][16] = 16384
        const unsigned short* Kp = kb + (size_t)((mode == 0) ? 0 : 3 * 32768);
        int obase = (mode == 0) ? 0 : 194;

        if (t < 256) {
            int l = t >> 4, c = t & 15;
            int grow = b * 128 + L0 + l;
            const float* ltrow = ltf + (size_t)grow * 512;
            const unsigned short* avrow = 0;
            if (mode == 2) avrow = rtb + ((size_t)(b * 128 + idxp[grow])) * 512;
            float csum = 0.f;
            #pragma unroll
            for (int pass = 0; pass < 4; ++pass) {
                int d0 = pass * 128 + c * 8;
                float lf[8], af[8], pf[8];
                *(float4*)&lf[0] = *(const float4*)(ltrow + d0);
                *(float4*)&lf[4] = *(const float4*)(ltrow + d0 + 4);
                if (mode == 0) {
                    const float* h = (d0 < 256) ? (hfw + b * 256 + d0) : (hbw + b * 256 + d0 - 256);
                    *(float4*)&af[0] = *(const float4*)h;
                    *(float4*)&af[4] = *(const float4*)(h + 4);
                } else {
                    uint4 av = *(const uint4*)(avrow + d0);
                    unpack8(av, af);
                }
                #pragma unroll
                for (int k = 0; k < 8; ++k) { pf[k] = lf[k] * af[k]; csum += pf[k]; }
                uint4 o;
                o.x = pack2(pf[0], pf[1]); o.y = pack2(pf[2], pf[3]);
                o.z = pack2(pf[4], pf[5]); o.w = pack2(pf[6], pf[7]);
                *(uint4*)&prods[l][d0] = o;
            }
            #pragma unroll
            for (int off = 1; off < 16; off <<= 1) csum += __shfl_xor(csum, off, 64);
            if (c == 0) out[(size_t)grow * 259 + obase] = tanhf(csum);
        }
        {   // stage all 64 K rows
            int row = t >> 3, c0 = (t & 7) * 64;
            const unsigned short* src = Kp + (size_t)row * 512 + c0;
            #pragma unroll
            for (int i = 0; i < 8; ++i)
                *(uint4*)&Ks[row * 520 + c0 + i * 8] = *(const uint4*)(src + i * 8);
        }
        __syncthreads();
        int hs = wave >> 2, w4 = wave & 3;
        float4v acc2[2] = {};
        #pragma unroll
        for (int kk = 0; kk < 128; kk += 32) {
            short8 af = *(const short8*)&prods[col][w4 * 128 + kk + kq];
            #pragma unroll
            for (int j = 0; j < 2; ++j) {
                short8 bf = *(const short8*)&Ks[(size_t)(hs * 32 + j * 16 + col) * 520 + w4 * 128 + kk + kq];
                acc2[j] = __builtin_amdgcn_mfma_f32_16x16x32_bf16(af, bf, acc2[j], 0, 0, 0);
            }
        }
        #pragma unroll
        for (int j = 0; j < 2; ++j)
            #pragma unroll
            for (int ii = 0; ii < 4; ++ii)
                red[(((hs * 4 + w4) * 2 + j) * 16 + (q * 4 + ii)) * 16 + col] = acc2[j][ii];
        __syncthreads();
        #pragma unroll
        for (int o = 0; o < 2; ++o) {
            int oo = t + o * 512;
            int ll = oo >> 6;
            int rem = oo & 63;
            int hh = rem >> 5, jm = rem & 31;
            int j = jm >> 4, mc = jm & 15;
            float s = 0.f;
            #pragma unroll
            for (int w = 0; w < 4; ++w) s += red[(((hh * 4 + w) * 2 + j) * 16 + ll) * 16 + mc];
            out[((size_t)(b * 128 + L0 + ll)) * 259 + obase + 1 + hh * 32 + jm] = tanhf(s);
        }
    }
}

// ---------------------------------------------------------------------------
extern "C" void kernel_launch(void* const* d_in, const int* in_sizes, int n_in,
                              void* d_out, int out_size, void* d_ws, size_t ws_size,
                              hipStream_t stream) {
    const float* lt  = (const float*)d_in[0];
    const float* rt  = (const float*)d_in[3];
    const float* hfw = (const float*)d_in[4];
    const float* hbw = (const float*)d_in[5];
    const float* kf  = (const float*)d_in[6];
    const float* kmp = (const float*)d_in[7];
    const float* w1  = (const float*)d_in[8];
    const float* dia = (const float*)d_in[9];
    const float* ka  = (const float*)d_in[10];
    const float* km  = (const float*)d_in[11];
    float* out = (float*)d_out;

    char* wsb = (char*)d_ws;
    unsigned short* ltb16 = (unsigned short*)(wsb);                        // 4 MB
    unsigned short* rtb16 = (unsigned short*)(wsb + 4194304);              // 4 MB
    unsigned short* kb16  = (unsigned short*)(wsb + 8388608);              // 256 KB
    unsigned short* w1t   = (unsigned short*)(wsb + 8650752);              // 128 KB
    unsigned short* a_all = (unsigned short*)(wsb + 8781824);              // 2 MB
    int*            idx   = (int*)(wsb + 15106048);                        // 16 KB

    prep_kernel<<<1216, 256, 0, stream>>>(lt, rt, kf, kmp, ka, km, w1, ltb16, rtb16, kb16, w1t);
    uber_kernel<<<2816, 256, 0, stream>>>(ltb16, rtb16, kb16 + 32768, w1t, dia, a_all,
                                          lt, rt, idx, out);
    tail_kernel<<<768, 512, 0, stream>>>(a_all, rtb16, lt, kb16, hfw, hbw, idx, out);
}

// Round 13
// 190.171 us; speedup vs baseline: 1.1522x; 1.1522x over previous
//
#include <hip/hip_runtime.h>
#include <hip/hip_bf16.h>
#include <math.h>
#include <stdint.h>

typedef __attribute__((ext_vector_type(8))) short short8;
typedef __attribute__((ext_vector_type(4))) float float4v;

#define DEV static __device__ __forceinline__

DEV float bflo(unsigned int u) { union { unsigned int i; float f; } v; v.i = u << 16; return v.f; }
DEV float bfhi(unsigned int u) { union { unsigned int i; float f; } v; v.i = u & 0xffff0000u; return v.f; }
DEV unsigned short f2bf(float f) {
    union { float f; unsigned int i; } v; v.f = f;
    unsigned int x = v.i;
    return (unsigned short)((x + 0x7fffu + ((x >> 16) & 1u)) >> 16);
}
DEV unsigned int pack2(float a, float b) { return (unsigned int)f2bf(a) | ((unsigned int)f2bf(b) << 16); }
#if __has_builtin(__builtin_amdgcn_cvt_pk_bf16_f32)
DEV unsigned int pack2_fast(float a, float b) {
    typedef __attribute__((ext_vector_type(2))) short short2v;
    short2v r = __builtin_amdgcn_cvt_pk_bf16_f32(a, b);
    union { short2v s; unsigned int u; } v; v.s = r; return v.u;
}
#else
DEV unsigned int pack2_fast(float a, float b) { return pack2(a, b); }
#endif
DEV void unpack8(uint4 u, float* f) {
    f[0]=bflo(u.x); f[1]=bfhi(u.x); f[2]=bflo(u.y); f[3]=bfhi(u.y);
    f[4]=bflo(u.z); f[5]=bfhi(u.z); f[6]=bflo(u.w); f[7]=bfhi(u.w);
}

DEV void async16(const unsigned short* g, unsigned short* l) {
    __builtin_amdgcn_global_load_lds(
        (const __attribute__((address_space(1))) unsigned int*)g,
        (__attribute__((address_space(3))) unsigned int*)l, 16, 0, 0);
}

// ---------------------------------------------------------------------------
// K0: prep = cast f32->bf16 (lt, rt, 4 match kernels) + rsq (f64) + w1 transpose
// ---------------------------------------------------------------------------
__global__ __launch_bounds__(256) void prep_kernel(const float* __restrict__ lt,
                                                   const float* __restrict__ rt,
                                                   const float* __restrict__ kf,
                                                   const float* __restrict__ kmp,
                                                   const float* __restrict__ ka,
                                                   const float* __restrict__ km,
                                                   const float* __restrict__ w1,
                                                   unsigned short* __restrict__ ltb,
                                                   unsigned short* __restrict__ rtb,
                                                   unsigned short* __restrict__ kb,
                                                   unsigned short* __restrict__ w1t,
                                                   double* __restrict__ rsq) {
    __shared__ double ws2[2][2];
    __shared__ float tile[32][33];
    int bid = blockIdx.x, t = threadIdx.x;
    if (bid < 1024) {
        bool isRt = bid >= 512;
        int base = (isRt ? (bid - 512) : bid) * 8;
        int rl = t >> 7;
        int c  = t & 127;
        const float* srcb = isRt ? rt : lt;
        unsigned short* dstb = isRt ? rtb : ltb;
        #pragma unroll
        for (int p = 0; p < 4; ++p) {
            int row = base + p * 2 + rl;
            const float* src = srcb + (size_t)row * 512;
            float4 v = *(const float4*)(src + c * 4);
            ushort4 o;
            o.x = f2bf(v.x); o.y = f2bf(v.y); o.z = f2bf(v.z); o.w = f2bf(v.w);
            *(ushort4*)(dstb + (size_t)row * 512 + c * 4) = o;
            if (isRt) {
                double s = (double)v.x * v.x + (double)v.y * v.y
                         + (double)v.z * v.z + (double)v.w * v.w;
                #pragma unroll
                for (int off = 1; off < 64; off <<= 1) s += __shfl_xor(s, off, 64);
                if ((c & 63) == 0) ws2[rl][c >> 6] = s;
                __syncthreads();
                if (c == 0) rsq[row] = 1.0 / sqrt(ws2[rl][0] + ws2[rl][1]);
                __syncthreads();
            }
        }
    } else if (bid < 1152) {
        int kbk = bid - 1024;
        int ksel = kbk >> 5;
        const float* src = (ksel == 0) ? kf : (ksel == 1) ? kmp : (ksel == 2) ? ka : km;
        int off = (kbk & 31) * 1024 + t * 4;
        float4 v = *(const float4*)(src + off);
        ushort4 o;
        o.x = f2bf(v.x); o.y = f2bf(v.y); o.z = f2bf(v.z); o.w = f2bf(v.w);
        *(ushort4*)(kb + ksel * 32768 + off) = o;
    } else {
        int b2 = bid - 1152;
        int d0 = (b2 & 15) * 32, a0 = (b2 >> 4) * 32;
        int r = t >> 5, c = t & 31;
        #pragma unroll
        for (int i = 0; i < 32; i += 8)
            tile[r + i][c] = w1[(size_t)(d0 + r + i) * 128 + a0 + c];
        __syncthreads();
        #pragma unroll
        for (int i = 0; i < 32; i += 8)
            w1t[(size_t)(a0 + r + i) * 512 + d0 + c] = f2bf(tile[c][r + i]);
    }
}

// ---------------------------------------------------------------------------
// K1: uber = mpool [0,2048) + argmax [2048,2560) + proj [2560,2816)
// mpool: R7 structure — single ltS, double async rtL, reg-prefetch lt/K,
// XCD swizzle, 2 barriers/k0, 3 blocks/CU.
// ---------------------------------------------------------------------------
__global__ __launch_bounds__(256, 3) void uber_kernel(
        const unsigned short* __restrict__ ltb,
        const unsigned short* __restrict__ rtb,
        const unsigned short* __restrict__ kmb,
        const unsigned short* __restrict__ w1t,
        const float* __restrict__ diag,
        unsigned short* __restrict__ a_all,
        const float* __restrict__ ltf,
        const float* __restrict__ rtf,
        const double* __restrict__ rsq,
        int* __restrict__ idxout,
        float* __restrict__ out) {
    __shared__ __align__(16) unsigned char smem[52224];
    int bx = blockIdx.x;
    int t = threadIdx.x;
    int wave = t >> 6, lane = t & 63;
    int q = lane >> 4, col = lane & 15, kq = q * 8;

    if (bx < 2048) {
        // ================= mpool role =================
        int xcd = bx & 7, jj = bx >> 3;
        int b = xcd * 4 + (jj >> 6);
        int m = jj & 63;
        unsigned short (*ltS)[72] = (unsigned short(*)[72])smem;        // 18432 B
        unsigned short* rtL = (unsigned short*)(smem + 18432);          // 2 x 16384 B, swizzled
        float (*mx)[2] = (float(*)[2])(smem + 18432 + 32768);          // 1024 B
        int wl = wave & 1, wr = wave >> 1;
        const unsigned short* ltp = ltb + (size_t)b * 65536;
        const unsigned short* rtp = rtb + (size_t)b * 65536;
        const unsigned short* kr = kmb + (size_t)m * 512;
        int srow = t >> 3, cg8 = t & 7, cg = cg8 * 8;
        int gsw = (cg8 ^ (srow & 7)) * 8;   // source-swizzled column group
        int wbase = (t & ~63) * 8;          // wave-uniform LDS base (shorts)

        // prologue: async rt(k0=0) -> buf0, lt/K(k0=0) -> regs
        #pragma unroll
        for (int it = 0; it < 4; ++it)
            async16(rtp + (size_t)(it * 32 + srow) * 512 + gsw,
                    rtL + it * 2048 + wbase);
        uint4 pk = *(const uint4*)(kr + cg);
        uint4 plt[4];
        #pragma unroll
        for (int it = 0; it < 4; ++it)
            plt[it] = *(const uint4*)(ltp + (size_t)(it * 32 + srow) * 512 + cg);

        float4v acc[4][4] = {};
        for (int k0i = 0; k0i < 8; ++k0i) {
            // scale+write ltS from prefetched regs
            float kf8[8]; unpack8(pk, kf8);
            #pragma unroll
            for (int it = 0; it < 4; ++it) {
                int row = it * 32 + srow;
                float lf[8]; unpack8(plt[it], lf);
                uint4 s;
                s.x = pack2_fast(lf[0] * kf8[0], lf[1] * kf8[1]);
                s.y = pack2_fast(lf[2] * kf8[2], lf[3] * kf8[3]);
                s.z = pack2_fast(lf[4] * kf8[4], lf[5] * kf8[5]);
                s.w = pack2_fast(lf[6] * kf8[6], lf[7] * kf8[7]);
                *(uint4*)&ltS[row][cg] = s;
            }
            __syncthreads();   // rt(k0) landed + lt staged
            if (k0i < 7) {     // prefetch k0+1: async rt + lt/K regs (fly during MFMA)
                int k0n = (k0i + 1) * 64;
                int bofs = ((k0i + 1) & 1) * 8192;
                #pragma unroll
                for (int it = 0; it < 4; ++it)
                    async16(rtp + (size_t)(it * 32 + srow) * 512 + k0n + gsw,
                            rtL + bofs + it * 2048 + wbase);
                pk = *(const uint4*)(kr + k0n + cg);
                #pragma unroll
                for (int it = 0; it < 4; ++it)
                    plt[it] = *(const uint4*)(ltp + (size_t)(it * 32 + srow) * 512 + k0n + cg);
            }
            const unsigned short* rb = rtL + (k0i & 1) * 8192;
            #pragma unroll
            for (int kk = 0; kk < 64; kk += 32) {
                short8 af[4], bfr[4];
                #pragma unroll
                for (int i = 0; i < 4; ++i)
                    af[i] = *(const short8*)&ltS[wl * 64 + i * 16 + col][kk + kq];
                #pragma unroll
                for (int j = 0; j < 4; ++j) {
                    int row = wr * 64 + j * 16 + col;
                    int slot = ((kk >> 3) + q) ^ (row & 7);
                    bfr[j] = *(const short8*)&rb[row * 64 + slot * 8];
                }
                #pragma unroll
                for (int i = 0; i < 4; ++i)
                    #pragma unroll
                    for (int j = 0; j < 4; ++j)
                        acc[i][j] = __builtin_amdgcn_mfma_f32_16x16x32_bf16(af[i], bfr[j], acc[i][j], 0, 0, 0);
            }
            __syncthreads();   // before ltS overwrite
        }
        #pragma unroll
        for (int i = 0; i < 4; ++i)
            #pragma unroll
            for (int ii = 0; ii < 4; ++ii) {
                float v = fmaxf(fmaxf(acc[i][0][ii], acc[i][1][ii]), fmaxf(acc[i][2][ii], acc[i][3][ii]));
                #pragma unroll
                for (int off = 1; off < 16; off <<= 1) v = fmaxf(v, __shfl_xor(v, off, 64));
                if (col == 0) mx[wl * 64 + i * 16 + q * 4 + ii][wr] = v;
            }
        __syncthreads();
        if (t < 128)
            out[((size_t)(b * 128 + t)) * 259 + 65 + m] = tanhf(fmaxf(mx[t][0], mx[t][1]));

    } else if (bx < 2560) {
        // ================= argmax role =================
        int idA = bx - 2048;
        int xcd = idA & 7, jj = idA >> 3;
        int b = xcd * 4 + (jj >> 4);
        int L0 = (jj & 15) * 8;
        float* ltS = (float*)smem;
        float* buf = (float*)(smem + 16384);
        double* dvs = (double*)(smem + 49152);
        float* wv1 = (float*)(smem + 49152 + 128);
        float* wv2 = wv1 + 16;
        int* wi1 = (int*)(wv2 + 16);
        int* wi2 = wi1 + 16;
        int* candi = wi2 + 16;
        {
            int row = t >> 5, c0 = (t & 31) * 16;
            const float* src = ltf + ((size_t)(b * 128 + L0 + row)) * 512 + c0;
            #pragma unroll
            for (int i = 0; i < 4; ++i)
                *(float4*)&ltS[row * 512 + c0 + i * 4] = *(const float4*)(src + i * 4);
        }
        int lg = t >> 7;
        int rg = (t >> 2) & 31;
        int ds = t & 3;
        float acc[4][4] = {{0.f}};
        for (int p = 0; p < 8; ++p) {
            __syncthreads();
            {
                int row = t >> 1, c0 = (t & 1) * 32;
                const float* src = rtf + ((size_t)(b * 128 + row)) * 512 + p * 64 + c0;
                float f[32];
                #pragma unroll
                for (int i = 0; i < 8; ++i)
                    *(float4*)&f[i * 4] = *(const float4*)(src + i * 4);
                int base = row * 64;
                #pragma unroll
                for (int gg = 0; gg < 4; ++gg) {
                    int g = (t & 1) * 4 + gg;
                    int o = ((g ^ (row & 7)) * 8);
                    #pragma unroll
                    for (int k = 0; k < 8; ++k) buf[base + o + k] = f[gg * 8 + k];
                }
            }
            __syncthreads();
            #pragma unroll
            for (int sub = 0; sub < 2; ++sub) {
                int dloc = ds * 16 + sub * 8;
                int dglob = p * 64 + dloc;
                float a[4][8];
                #pragma unroll
                for (int i = 0; i < 4; ++i)
                    #pragma unroll
                    for (int k = 0; k < 8; ++k) a[i][k] = ltS[(lg * 4 + i) * 512 + dglob + k];
                int g = dloc >> 3;
                #pragma unroll
                for (int j = 0; j < 4; ++j) {
                    int r = rg + j * 32;
                    const float* rp = &buf[r * 64 + ((g ^ (r & 7)) * 8)];
                    float rv[8];
                    #pragma unroll
                    for (int k = 0; k < 8; ++k) rv[k] = rp[k];
                    #pragma unroll
                    for (int i = 0; i < 4; ++i)
                        #pragma unroll
                        for (int k = 0; k < 8; ++k)
                            acc[i][j] = fmaf(a[i][k], rv[k], acc[i][j]);
                }
            }
        }
        #pragma unroll
        for (int i = 0; i < 4; ++i)
            #pragma unroll
            for (int j = 0; j < 4; ++j) {
                acc[i][j] += __shfl_xor(acc[i][j], 1, 64);
                acc[i][j] += __shfl_xor(acc[i][j], 2, 64);
            }
        float v1[4], v2[4]; int i1[4], i2[4];
        #pragma unroll
        for (int i = 0; i < 4; ++i) {
            v1[i] = -3.0e38f; v2[i] = -3.0e38f; i1[i] = 0; i2[i] = 1;
            #pragma unroll
            for (int j = 0; j < 4; ++j) {
                int r = rg + j * 32;
                float s = acc[i][j] * (float)rsq[b * 128 + r];
                if (s > v1[i]) { v2[i] = v1[i]; i2[i] = i1[i]; v1[i] = s; i1[i] = r; }
                else if (s > v2[i]) { v2[i] = s; i2[i] = r; }
            }
        }
        #pragma unroll
        for (int off = 4; off < 64; off <<= 1) {
            #pragma unroll
            for (int i = 0; i < 4; ++i) {
                float u1 = __shfl_xor(v1[i], off, 64); int j1 = __shfl_xor(i1[i], off, 64);
                float u2 = __shfl_xor(v2[i], off, 64); int j2 = __shfl_xor(i2[i], off, 64);
                if (u1 > v1[i]) {
                    float ov = v1[i]; int oi = i1[i];
                    v1[i] = u1; i1[i] = j1;
                    if (u2 > ov) { v2[i] = u2; i2[i] = j2; } else { v2[i] = ov; i2[i] = oi; }
                } else if (u1 > v2[i]) { v2[i] = u1; i2[i] = j1; }
            }
        }
        if (lane == 0) {
            #pragma unroll
            for (int i = 0; i < 4; ++i) {
                int l = lg * 4 + i, h = wave & 1;
                wv1[l * 2 + h] = v1[i]; wi1[l * 2 + h] = i1[i];
                wv2[l * 2 + h] = v2[i]; wi2[l * 2 + h] = i2[i];
            }
        }
        __syncthreads();
        if (t < 8) {
            float a1 = wv1[t * 2], a2 = wv2[t * 2]; int ai1 = wi1[t * 2], ai2 = wi2[t * 2];
            float b1 = wv1[t * 2 + 1], b2 = wv2[t * 2 + 1]; int bi1 = wi1[t * 2 + 1], bi2 = wi2[t * 2 + 1];
            int ri1, ri2;
            if (b1 > a1) {
                ri1 = bi1;
                if (b2 > a1) { ri2 = bi2; } else { ri2 = ai1; }
            } else {
                ri1 = ai1;
                if (b1 > a2) { ri2 = bi1; } else { ri2 = ai2; }
            }
            candi[t * 2] = ri1; candi[t * 2 + 1] = ri2;
            (void)a2; (void)b2; (void)ai2; (void)bi2;
        }
        __syncthreads();
        {
            int dotid = t >> 4;
            int sub = t & 15;
            int l = dotid >> 1, c = dotid & 1;
            int r = candi[l * 2 + c];
            const float* lrow = ltf + ((size_t)(b * 128 + L0 + l)) * 512;
            const float* rrow = rtf + ((size_t)(b * 128 + r)) * 512;
            double s = 0.0;
            #pragma unroll 8
            for (int k = 0; k < 32; ++k) {
                int d = sub * 32 + k;
                s = fma((double)lrow[d], (double)rrow[d], s);
            }
            #pragma unroll
            for (int off = 1; off < 16; off <<= 1) s += __shfl_xor(s, off, 64);
            if (sub == 0) dvs[l * 2 + c] = s * rsq[b * 128 + r];
        }
        __syncthreads();
        if (t < 8) {
            int ia = candi[t * 2], ib = candi[t * 2 + 1];
            double va = dvs[t * 2], vb = dvs[t * 2 + 1];
            int res = (vb > va || (vb == va && ib < ia)) ? ib : ia;
            idxout[b * 128 + L0 + t] = res;
        }

    } else {
        // ================= proj role =================
        int R0 = (bx - 2560) * 32;
        unsigned short (*aS)[72] = (unsigned short(*)[72])smem;
        unsigned short (*bS)[72] = (unsigned short(*)[72])(smem + 4608);
        float* diagS = (float*)(smem + 4608 + 18432);
        int wl = wave & 1, wr = wave >> 1;
        if (t < 128) diagS[t] = diag[t];
        const unsigned short* src = (R0 < 4096) ? (ltb + (size_t)R0 * 512) : (rtb + (size_t)(R0 - 4096) * 512);
        float4v acc[4] = {};
        for (int k0 = 0; k0 < 512; k0 += 64) {
            {
                int row = t >> 3, cg = (t & 7) * 8;
                *(uint4*)&aS[row][cg] = *(const uint4*)(src + (size_t)row * 512 + k0 + cg);
            }
            #pragma unroll
            for (int it = 0; it < 4; ++it) {
                int id = it * 256 + t;
                int row = id >> 3, cg = (id & 7) * 8;
                *(uint4*)&bS[row][cg] = *(const uint4*)(w1t + (size_t)row * 512 + k0 + cg);
            }
            __syncthreads();
            #pragma unroll
            for (int kk = 0; kk < 64; kk += 32) {
                short8 af = *(const short8*)&aS[wl * 16 + col][kk + kq];
                #pragma unroll
                for (int j = 0; j < 4; ++j) {
                    short8 bf = *(const short8*)&bS[wr * 64 + j * 16 + col][kk + kq];
                    acc[j] = __builtin_amdgcn_mfma_f32_16x16x32_bf16(af, bf, acc[j], 0, 0, 0);
                }
            }
            __syncthreads();
        }
        bool isLt = (R0 < 4096);
        #pragma unroll
        for (int j = 0; j < 4; ++j)
            #pragma unroll
            for (int ii = 0; ii < 4; ++ii) {
                int rowl = wl * 16 + q * 4 + ii;
                int n = wr * 64 + j * 16 + col;
                float v = tanhf(acc[j][ii]);
                if (isLt) v *= diagS[n];
                a_all[((size_t)(R0 + rowl)) * 128 + n] = f2bf(v);
            }
    }
}

// ---------------------------------------------------------------------------
// K2: tail = attn+fused-mode1 [0,256) + mpmatch sequential-halves [256,768)
// 512 threads, LDS 81664 B -> 2 blocks/CU (needs VGPR<=128: bounds (512,4)).
// ---------------------------------------------------------------------------
__global__ __launch_bounds__(512, 4) void tail_kernel(
        const unsigned short* __restrict__ a_all,
        const unsigned short* __restrict__ rtb,
        const float* __restrict__ ltf,
        const unsigned short* __restrict__ kb,
        const float* __restrict__ hfw,
        const float* __restrict__ hbw,
        const int* __restrict__ idxp,
        float* __restrict__ out) {
    __shared__ __align__(16) unsigned char smem[81664];
    int bx = blockIdx.x;
    int t = threadIdx.x;
    int wave = t >> 6, lane = t & 63;
    int q = lane >> 4, col = lane & 15, kq = q * 8;

    if (bx < 256) {
        // ================= attn role =================
        int b = bx & 31, lg = bx >> 5;
        int L0 = lg * 16;
        unsigned short (*altS)[136]  = (unsigned short(*)[136])(smem);          // 4352
        unsigned short (*artS)[136]  = (unsigned short(*)[136])(smem + 4352);   // 34816
        unsigned short (*rtS)[512]   = (unsigned short(*)[512])(smem + 39168);  // 16384
        unsigned short (*prodsF)[520]= (unsigned short(*)[520])(smem + 55552);  // 16640
        float (*P)[132]  = (float(*)[132])(smem + 72192);                       // 8448
        float (*pmax)[8] = (float(*)[8])(smem + 80640);                         // 512
        float (*psum)[8] = (float(*)[8])(smem + 81152);                         // 512
        const unsigned short* kb_att = kb + 2 * 32768;

        if (t < 256) {
            int row = t >> 4, c0 = (t & 15) * 8;
            *(uint4*)&altS[row][c0] = *(const uint4*)(a_all + ((size_t)(b * 128 + L0 + row)) * 128 + c0);
        }
        {
            int row = t >> 2, c0 = (t & 3) * 32;
            const unsigned short* src = a_all + ((size_t)(4096 + b * 128 + row)) * 128 + c0;
            #pragma unroll
            for (int i = 0; i < 4; ++i)
                *(uint4*)&artS[row][c0 + i * 8] = *(const uint4*)(src + i * 8);
        }
        __syncthreads();

        float4v acc = {};
        #pragma unroll
        for (int kk = 0; kk < 128; kk += 32) {
            short8 af = *(const short8*)&altS[col][kk + kq];
            short8 bf = *(const short8*)&artS[wave * 16 + col][kk + kq];
            acc = __builtin_amdgcn_mfma_f32_16x16x32_bf16(af, bf, acc, 0, 0, 0);
        }
        float m4[4], p4[4];
        #pragma unroll
        for (int ii = 0; ii < 4; ++ii) {
            float v = acc[ii];
            #pragma unroll
            for (int off = 1; off < 16; off <<= 1) v = fmaxf(v, __shfl_xor(v, off, 64));
            m4[ii] = v;
        }
        if (col == 0) {
            #pragma unroll
            for (int ii = 0; ii < 4; ++ii) pmax[q * 4 + ii][wave] = m4[ii];
        }
        __syncthreads();
        #pragma unroll
        for (int ii = 0; ii < 4; ++ii) {
            float M = pmax[q * 4 + ii][0];
            #pragma unroll
            for (int w = 1; w < 8; ++w) M = fmaxf(M, pmax[q * 4 + ii][w]);
            p4[ii] = expf(acc[ii] - M);
            float s = p4[ii];
            #pragma unroll
            for (int off = 1; off < 16; off <<= 1) s += __shfl_xor(s, off, 64);
            m4[ii] = s;
        }
        if (col == 0) {
            #pragma unroll
            for (int ii = 0; ii < 4; ++ii) psum[q * 4 + ii][wave] = m4[ii];
        }
        __syncthreads();
        #pragma unroll
        for (int ii = 0; ii < 4; ++ii) {
            float S = psum[q * 4 + ii][0] + psum[q * 4 + ii][1] + psum[q * 4 + ii][2] + psum[q * 4 + ii][3]
                    + psum[q * 4 + ii][4] + psum[q * 4 + ii][5] + psum[q * 4 + ii][6] + psum[q * 4 + ii][7];
            P[q * 4 + ii][wave * 16 + col] = p4[ii] / S;
        }

        int l = t >> 5, cd = t & 31;
        float a8[2][8] = {{0.f}};
        for (int rcb = 0; rcb < 128; rcb += 16) {
            __syncthreads();
            {
                int row = t >> 5, c0 = (t & 31) * 16;
                const unsigned short* src = rtb + ((size_t)(b * 128 + rcb + row)) * 512 + c0;
                *(uint4*)&rtS[row][c0] = *(const uint4*)src;
                *(uint4*)&rtS[row][c0 + 8] = *(const uint4*)(src + 8);
            }
            __syncthreads();
            for (int rr = 0; rr < 16; ++rr) {
                float pr = P[l][rcb + rr];
                #pragma unroll
                for (int pass = 0; pass < 2; ++pass) {
                    uint4 u = *(const uint4*)&rtS[rr][pass * 256 + cd * 8];
                    float f[8]; unpack8(u, f);
                    #pragma unroll
                    for (int k = 0; k < 8; ++k) a8[pass][k] += pr * f[k];
                }
            }
        }

        int grow = b * 128 + L0 + l;
        const float* ltrow = ltf + (size_t)grow * 512;
        float csum = 0.f;
        #pragma unroll
        for (int pass = 0; pass < 2; ++pass) {
            int d0 = pass * 256 + cd * 8;
            float lf[8];
            *(float4*)&lf[0] = *(const float4*)(ltrow + d0);
            *(float4*)&lf[4] = *(const float4*)(ltrow + d0 + 4);
            float pf[8];
            #pragma unroll
            for (int k = 0; k < 8; ++k) { pf[k] = lf[k] * a8[pass][k]; csum += pf[k]; }
            uint4 o;
            o.x = pack2(pf[0], pf[1]); o.y = pack2(pf[2], pf[3]);
            o.z = pack2(pf[4], pf[5]); o.w = pack2(pf[6], pf[7]);
            *(uint4*)&prodsF[l][d0] = o;
        }
        #pragma unroll
        for (int off = 1; off < 32; off <<= 1) csum += __shfl_xor(csum, off, 64);
        if (cd == 0) out[(size_t)grow * 259 + 129] = tanhf(csum);

        unsigned short* Ks = &artS[0][0];
        float* red = (float*)&rtS[0][0];
        for (int half = 0; half < 2; ++half) {
            __syncthreads();
            {
                int row = t >> 4, c0 = (t & 15) * 32;
                const unsigned short* src = kb_att + ((size_t)(half * 32 + row)) * 512 + c0;
                #pragma unroll
                for (int i = 0; i < 4; ++i)
                    *(uint4*)&Ks[row * 520 + c0 + i * 8] = *(const uint4*)(src + i * 8);
            }
            __syncthreads();
            float4v pacc[2] = {};
            #pragma unroll
            for (int kk = 0; kk < 64; kk += 32) {
                short8 af = *(const short8*)&prodsF[col][wave * 64 + kk + kq];
                #pragma unroll
                for (int j = 0; j < 2; ++j) {
                    short8 bf = *(const short8*)&Ks[(j * 16 + col) * 520 + wave * 64 + kk + kq];
                    pacc[j] = __builtin_amdgcn_mfma_f32_16x16x32_bf16(af, bf, pacc[j], 0, 0, 0);
                }
            }
            #pragma unroll
            for (int j = 0; j < 2; ++j)
                #pragma unroll
                for (int ii = 0; ii < 4; ++ii)
                    red[((wave * 2 + j) * 16 + q * 4 + ii) * 16 + col] = pacc[j][ii];
            __syncthreads();
            {
                int ll = t >> 5, jm = t & 31;
                int j = jm >> 4, mc = jm & 15;
                float s = 0.f;
                #pragma unroll
                for (int w = 0; w < 8; ++w) s += red[((w * 2 + j) * 16 + ll) * 16 + mc];
                out[((size_t)(b * 128 + L0 + ll)) * 259 + 130 + half * 32 + jm] = tanhf(s);
            }
        }

    } else {
        // ================= mpmatch role (sequential 32-m halves) =================
        int idB = bx - 256;
        int lg = idB & 7, b = (idB >> 3) & 31;
        int mode = (idB >> 8) ? 2 : 0;
        int L0 = lg * 16;
        unsigned short (*prods)[520] = (unsigned short(*)[520])smem;            // 16640
        unsigned short* Ks = (unsigned short*)(smem + 16640);                   // 32*520*2 = 33280
        float* red = (float*)(smem + 49920);                                    // [8][2][16][16] = 16384
        const unsigned short* Kp = kb + (size_t)((mode == 0) ? 0 : 3 * 32768);
        int obase = (mode == 0) ? 0 : 194;

        if (t < 256) {
            int l = t >> 4, c = t & 15;
            int grow = b * 128 + L0 + l;
            const float* ltrow = ltf + (size_t)grow * 512;
            const unsigned short* avrow = 0;
            if (mode == 2) avrow = rtb + ((size_t)(b * 128 + idxp[grow])) * 512;
            float csum = 0.f;
            #pragma unroll
            for (int pass = 0; pass < 4; ++pass) {
                int d0 = pass * 128 + c * 8;
                float lf[8], af[8], pf[8];
                *(float4*)&lf[0] = *(const float4*)(ltrow + d0);
                *(float4*)&lf[4] = *(const float4*)(ltrow + d0 + 4);
                if (mode == 0) {
                    const float* h = (d0 < 256) ? (hfw + b * 256 + d0) : (hbw + b * 256 + d0 - 256);
                    *(float4*)&af[0] = *(const float4*)h;
                    *(float4*)&af[4] = *(const float4*)(h + 4);
                } else {
                    uint4 av = *(const uint4*)(avrow + d0);
                    unpack8(av, af);
                }
                #pragma unroll
                for (int k = 0; k < 8; ++k) { pf[k] = lf[k] * af[k]; csum += pf[k]; }
                uint4 o;
                o.x = pack2(pf[0], pf[1]); o.y = pack2(pf[2], pf[3]);
                o.z = pack2(pf[4], pf[5]); o.w = pack2(pf[6], pf[7]);
                *(uint4*)&prods[l][d0] = o;
            }
            #pragma unroll
            for (int off = 1; off < 16; off <<= 1) csum += __shfl_xor(csum, off, 64);
            if (c == 0) out[(size_t)grow * 259 + obase] = tanhf(csum);
        }
        for (int half = 0; half < 2; ++half) {
            {   // stage 32 K rows (512 threads, 32B each)
                int row = t >> 4, c0 = (t & 15) * 32;
                const unsigned short* src = Kp + ((size_t)(half * 32 + row)) * 512 + c0;
                #pragma unroll
                for (int i = 0; i < 4; ++i)
                    *(uint4*)&Ks[row * 520 + c0 + i * 8] = *(const uint4*)(src + i * 8);
            }
            __syncthreads();   // prods + Ks ready
            float4v acc2[2] = {};
            #pragma unroll
            for (int kk = 0; kk < 64; kk += 32) {
                short8 af = *(const short8*)&prods[col][wave * 64 + kk + kq];
                #pragma unroll
                for (int j = 0; j < 2; ++j) {
                    short8 bf = *(const short8*)&Ks[(j * 16 + col) * 520 + wave * 64 + kk + kq];
                    acc2[j] = __builtin_amdgcn_mfma_f32_16x16x32_bf16(af, bf, acc2[j], 0, 0, 0);
                }
            }
            #pragma unroll
            for (int j = 0; j < 2; ++j)
                #pragma unroll
                for (int ii = 0; ii < 4; ++ii)
                    red[((wave * 2 + j) * 16 + q * 4 + ii) * 16 + col] = acc2[j][ii];
            __syncthreads();   // red ready (also guards Ks restage next iter)
            {
                int ll = t >> 5, jm = t & 31;
                int j = jm >> 4, mc = jm & 15;
                float s = 0.f;
                #pragma unroll
                for (int w = 0; w < 8; ++w) s += red[((w * 2 + j) * 16 + ll) * 16 + mc];
                out[((size_t)(b * 128 + L0 + ll)) * 259 + obase + 1 + half * 32 + jm] = tanhf(s);
            }
            __syncthreads();   // red reads done before next half overwrites
        }
    }
}

// ---------------------------------------------------------------------------
extern "C" void kernel_launch(void* const* d_in, const int* in_sizes, int n_in,
                              void* d_out, int out_size, void* d_ws, size_t ws_size,
                              hipStream_t stream) {
    const float* lt  = (const float*)d_in[0];
    const float* rt  = (const float*)d_in[3];
    const float* hfw = (const float*)d_in[4];
    const float* hbw = (const float*)d_in[5];
    const float* kf  = (const float*)d_in[6];
    const float* kmp = (const float*)d_in[7];
    const float* w1  = (const float*)d_in[8];
    const float* dia = (const float*)d_in[9];
    const float* ka  = (const float*)d_in[10];
    const float* km  = (const float*)d_in[11];
    float* out = (float*)d_out;

    char* wsb = (char*)d_ws;
    unsigned short* ltb16 = (unsigned short*)(wsb);                        // 4 MB
    unsigned short* rtb16 = (unsigned short*)(wsb + 4194304);              // 4 MB
    unsigned short* kb16  = (unsigned short*)(wsb + 8388608);              // 256 KB
    unsigned short* w1t   = (unsigned short*)(wsb + 8650752);              // 128 KB
    unsigned short* a_all = (unsigned short*)(wsb + 8781824);              // 2 MB
    double*         rsq   = (double*)(wsb + 15073280);                     // 32 KB
    int*            idx   = (int*)(wsb + 15106048);                        // 16 KB

    prep_kernel<<<1216, 256, 0, stream>>>(lt, rt, kf, kmp, ka, km, w1, ltb16, rtb16, kb16, w1t, rsq);
    uber_kernel<<<2816, 256, 0, stream>>>(ltb16, rtb16, kb16 + 32768, w1t, dia, a_all,
                                          lt, rt, rsq, idx, out);
    tail_kernel<<<768, 512, 0, stream>>>(a_all, rtb16, lt, kb16, hfw, hbw, idx, out);
}